// Round 4
// baseline (3496.691 us; speedup 1.0000x reference)
//
#include <hip/hip_runtime.h>
#include <hip/hip_bf16.h>

#define TT 128   // time steps
#define BB 1024  // batch
#define DD 256   // deter dim
#define SS 32    // stoch dim

typedef __attribute__((ext_vector_type(8))) short bf16x8;
typedef __attribute__((ext_vector_type(4))) float f32x4;

__device__ __forceinline__ float eluf(float x)   { return x > 0.f ? x : __expf(x) - 1.f; }
__device__ __forceinline__ float sigf(float x)   { return 1.f / (1.f + __expf(-x)); }
__device__ __forceinline__ float tanhf_(float x) { float e = __expf(2.f * x); return (e - 1.f) / (e + 1.f); }
__device__ __forceinline__ float clip75(float x) { return fminf(fmaxf(x, -7.f), 5.f); }

#define MFMA(a, b, c) __builtin_amdgcn_mfma_f32_16x16x32_bf16((a), (b), (c), 0, 0, 0)

// ---------------- generic B-fragment prep ----------------
// dst[((nt*(Kpad/32)+ks)*64+lane)*8+j] = src[(nt*16+(lane&15))*ld + coff + k],  k = ks*32+(lane>>4)*8+j
// zero when k >= Ksrc (K padding)
__global__ void prep_frag(const float* __restrict__ src, __hip_bfloat16* __restrict__ dst,
                          int N, int Kpad, int Ksrc, int ld, int coff)
{
    int idx = blockIdx.x * 256 + threadIdx.x;
    if (idx >= N * Kpad) return;
    int j = idx & 7, lane = (idx >> 3) & 63;
    int rest = idx >> 9;
    int nks = Kpad >> 5;
    int ks = rest % nks, nt = rest / nks;
    int n = nt * 16 + (lane & 15);
    int k = ks * 32 + (lane >> 4) * 8 + j;
    float v = (k < Ksrc) ? src[(size_t)n * ld + coff + k] : 0.f;
    dst[idx] = __float2bfloat16(v);
}

// ---------------- obs encoder (MFMA): 32 rows/block, 3 layers, writes Qpre fp32 ----------------
__global__ void __launch_bounds__(256) obs_enc_k(
    const float* __restrict__ obs,
    const __hip_bfloat16* __restrict__ We1f, const float* __restrict__ be1,
    const __hip_bfloat16* __restrict__ We2f, const float* __restrict__ be2,
    const __hip_bfloat16* __restrict__ Wq1ef, const float* __restrict__ bq1,
    float* __restrict__ Qpre)
{
    __shared__ __hip_bfloat16 A0[32][72];
    __shared__ __hip_bfloat16 A1[32][264];
    __shared__ __hip_bfloat16 A2[32][264];
    const int tid = threadIdx.x, wv = tid >> 6, lane = tid & 63;
    const int r0 = blockIdx.x * 32;
    const int am = lane & 15, aq = lane >> 4;

    for (int i = tid; i < 32 * 64; i += 256) {
        int r = i >> 6, k = i & 63;
        A0[r][k] = __float2bfloat16(obs[(size_t)(r0 + r) * 64 + k]);
    }
    __syncthreads();

    // L1: K=64 -> 256 cols
    {
        bf16x8 a[2][2];
#pragma unroll
        for (int mt = 0; mt < 2; ++mt)
#pragma unroll
            for (int ks = 0; ks < 2; ++ks)
                a[mt][ks] = *(const bf16x8*)&A0[mt * 16 + am][ks * 32 + aq * 8];
#pragma unroll
        for (int i = 0; i < 4; ++i) {
            int nt = wv * 4 + i;
            bf16x8 b0 = ((const bf16x8*)We1f)[(nt * 2 + 0) * 64 + lane];
            bf16x8 b1 = ((const bf16x8*)We1f)[(nt * 2 + 1) * 64 + lane];
            int col = nt * 16 + am;
            float bias = be1[col];
#pragma unroll
            for (int mt = 0; mt < 2; ++mt) {
                f32x4 acc = {0.f, 0.f, 0.f, 0.f};
                acc = MFMA(a[mt][0], b0, acc);
                acc = MFMA(a[mt][1], b1, acc);
#pragma unroll
                for (int reg = 0; reg < 4; ++reg)
                    A1[mt * 16 + aq * 4 + reg][col] = __float2bfloat16(eluf(acc[reg] + bias));
            }
        }
    }
    __syncthreads();

    // L2: K=256 -> 256 cols
    {
        bf16x8 a[2][8];
#pragma unroll
        for (int mt = 0; mt < 2; ++mt)
#pragma unroll
            for (int ks = 0; ks < 8; ++ks)
                a[mt][ks] = *(const bf16x8*)&A1[mt * 16 + am][ks * 32 + aq * 8];
#pragma unroll
        for (int i = 0; i < 4; ++i) {
            int nt = wv * 4 + i;
            bf16x8 b[8];
#pragma unroll
            for (int ks = 0; ks < 8; ++ks) b[ks] = ((const bf16x8*)We2f)[(nt * 8 + ks) * 64 + lane];
            int col = nt * 16 + am;
            float bias = be2[col];
#pragma unroll
            for (int mt = 0; mt < 2; ++mt) {
                f32x4 acc = {0.f, 0.f, 0.f, 0.f};
#pragma unroll
                for (int ks = 0; ks < 8; ++ks) acc = MFMA(a[mt][ks], b[ks], acc);
#pragma unroll
                for (int reg = 0; reg < 4; ++reg)
                    A2[mt * 16 + aq * 4 + reg][col] = __float2bfloat16(eluf(acc[reg] + bias));
            }
        }
    }
    __syncthreads();

    // L3: K=256 -> Qpre (fp32, + b_q1, no activation)
    {
        bf16x8 a[2][8];
#pragma unroll
        for (int mt = 0; mt < 2; ++mt)
#pragma unroll
            for (int ks = 0; ks < 8; ++ks)
                a[mt][ks] = *(const bf16x8*)&A2[mt * 16 + am][ks * 32 + aq * 8];
#pragma unroll
        for (int i = 0; i < 4; ++i) {
            int nt = wv * 4 + i;
            bf16x8 b[8];
#pragma unroll
            for (int ks = 0; ks < 8; ++ks) b[ks] = ((const bf16x8*)Wq1ef)[(nt * 8 + ks) * 64 + lane];
            int col = nt * 16 + am;
            float bias = bq1[col];
#pragma unroll
            for (int mt = 0; mt < 2; ++mt) {
                f32x4 acc = {0.f, 0.f, 0.f, 0.f};
#pragma unroll
                for (int ks = 0; ks < 8; ++ks) acc = MFMA(a[mt][ks], b[ks], acc);
#pragma unroll
                for (int reg = 0; reg < 4; ++reg) {
                    int row = r0 + mt * 16 + aq * 4 + reg;
                    int bb = row >> 7, t = row & (TT - 1);   // row = b*T + t
                    Qpre[((size_t)t * BB + bb) * 256 + col] = acc[reg] + bias;
                }
            }
        }
    }
}

// ---------------- prior net (off critical path): reads h from out, writes pm|ps ----------------
__global__ void __launch_bounds__(256) prior_k(
    const __hip_bfloat16* __restrict__ Wp1f, const float* __restrict__ bp1,
    const __hip_bfloat16* __restrict__ Wp2f, const float* __restrict__ bp2,
    float* __restrict__ out)
{
    __shared__ __hip_bfloat16 A0[32][264];
    __shared__ __hip_bfloat16 A1[32][264];
    const int tid = threadIdx.x, wv = tid >> 6, lane = tid & 63;
    const int r0 = blockIdx.x * 32;
    const int am = lane & 15, aq = lane >> 4;

    for (int i = tid; i < 32 * 256; i += 256) {
        int r = i >> 8, k = i & 255;
        A0[r][k] = __float2bfloat16(out[(size_t)(r0 + r) * 416 + k]);   // h
    }
    __syncthreads();

    // L1: P1 = elu(h @ Wp1^T + bp1), K=256
    {
        bf16x8 a[2][8];
#pragma unroll
        for (int mt = 0; mt < 2; ++mt)
#pragma unroll
            for (int ks = 0; ks < 8; ++ks)
                a[mt][ks] = *(const bf16x8*)&A0[mt * 16 + am][ks * 32 + aq * 8];
#pragma unroll
        for (int i = 0; i < 4; ++i) {
            int nt = wv * 4 + i;
            bf16x8 b[8];
#pragma unroll
            for (int ks = 0; ks < 8; ++ks) b[ks] = ((const bf16x8*)Wp1f)[(nt * 8 + ks) * 64 + lane];
            int col = nt * 16 + am;
            float bias = bp1[col];
#pragma unroll
            for (int mt = 0; mt < 2; ++mt) {
                f32x4 acc = {0.f, 0.f, 0.f, 0.f};
#pragma unroll
                for (int ks = 0; ks < 8; ++ks) acc = MFMA(a[mt][ks], b[ks], acc);
#pragma unroll
                for (int reg = 0; reg < 4; ++reg)
                    A1[mt * 16 + aq * 4 + reg][col] = __float2bfloat16(eluf(acc[reg] + bias));
            }
        }
    }
    __syncthreads();

    // L2: stats (64 cols), wave wv handles N-tile wv
    {
        bf16x8 a[2][8];
#pragma unroll
        for (int mt = 0; mt < 2; ++mt)
#pragma unroll
            for (int ks = 0; ks < 8; ++ks)
                a[mt][ks] = *(const bf16x8*)&A1[mt * 16 + am][ks * 32 + aq * 8];
        bf16x8 b[8];
#pragma unroll
        for (int ks = 0; ks < 8; ++ks) b[ks] = ((const bf16x8*)Wp2f)[(wv * 8 + ks) * 64 + lane];
        int c = wv * 16 + am;
        float bias = bp2[c];
#pragma unroll
        for (int mt = 0; mt < 2; ++mt) {
            f32x4 acc = {0.f, 0.f, 0.f, 0.f};
#pragma unroll
            for (int ks = 0; ks < 8; ++ks) acc = MFMA(a[mt][ks], b[ks], acc);
#pragma unroll
            for (int reg = 0; reg < 4; ++reg) {
                int row = r0 + mt * 16 + aq * 4 + reg;
                float v = acc[reg] + bias;
                out[(size_t)row * 416 + 288 + c] = (c < 32) ? v : __expf(clip75(v));
            }
        }
    }
}

// ---------------- sequential kernel: 256 blocks x 512 threads, 4 batch rows each ----------------
__global__ void __launch_bounds__(512, 1) rssm_seq(
    const float* __restrict__ act, const float* __restrict__ noise,
    const __hip_bfloat16* __restrict__ WAf,   // Q1 h-part (nt 0..15) | gh (nt 16..63), K=256
    const __hip_bfloat16* __restrict__ Wq2f,  // posterior stats, 4 tiles, K=256
    const __hip_bfloat16* __restrict__ Wihf,  // GRU input, 48 tiles, Kpad=64
    const float* __restrict__ b_hh, const float* __restrict__ b_ih,
    const float* __restrict__ b_q2, const float* __restrict__ Qpre,
    float* __restrict__ out)
{
    __shared__ __hip_bfloat16 hbf[16][264];   // A-frag: h (rows 0-3 real)
    __shared__ __hip_bfloat16 q1bf[16][264];  // A-frag: elu(Q1)
    __shared__ __hip_bfloat16 xbf[16][72];    // A-frag: [z|act], Kpad=64
    __shared__ float ghl[4][768];
    __shared__ float gil[4][768];
    __shared__ float sq[4][64];
    __shared__ float h32[4][256];
    __shared__ float qpl[4][256];
    __shared__ float bhh[768];
    __shared__ float bih[768];
    __shared__ float bq2l[64];

    const int tid = threadIdx.x;
    const int wv = tid >> 6, lane = tid & 63;
    const int blk = blockIdx.x;
    const int am = lane & 15, aq = lane >> 4;

    for (int i = tid; i < 16 * 264; i += 512) {
        ((unsigned short*)hbf)[i] = 0;
        ((unsigned short*)q1bf)[i] = 0;
    }
    for (int i = tid; i < 16 * 72; i += 512) ((unsigned short*)xbf)[i] = 0;
    for (int i = tid; i < 1024; i += 512) ((float*)h32)[i] = 0.f;
    for (int i = tid; i < 768; i += 512) { bhh[i] = b_hh[i]; bih[i] = b_ih[i]; }
    if (tid < 64) bq2l[tid] = b_q2[tid];
    for (int i = tid; i < 1024; i += 512) {
        int r = i >> 8, c = i & 255;
        qpl[r][c] = Qpre[((size_t)0 * BB + blk * 4 + r) * 256 + c];
    }
    __syncthreads();

    const bf16x8* wpA = (const bf16x8*)WAf;
    const bf16x8* wpQ = (const bf16x8*)Wq2f;
    const bf16x8* wpI = (const bf16x8*)Wihf;

    for (int t = 0; t < TT; ++t) {
        // ---- Phase A: [Q1|gh] = h @ WA^T ; 8 tiles per wave, double-buffered ----
        bf16x8 afr[8];
#pragma unroll
        for (int ks = 0; ks < 8; ++ks)
            afr[ks] = *(const bf16x8*)&hbf[am][ks * 32 + aq * 8];

        const int nt0 = wv * 8;
        bf16x8 bb[2][8];
#pragma unroll
        for (int ks = 0; ks < 8; ++ks) bb[0][ks] = wpA[(nt0 * 8 + ks) * 64 + lane];
#pragma unroll
        for (int i = 0; i < 8; ++i) {
            const int cb = i & 1;
            if (i < 7) {
#pragma unroll
                for (int ks = 0; ks < 8; ++ks)
                    bb[cb ^ 1][ks] = wpA[((nt0 + i + 1) * 8 + ks) * 64 + lane];
            }
            f32x4 acc = {0.f, 0.f, 0.f, 0.f};
#pragma unroll
            for (int ks = 0; ks < 8; ++ks) acc = MFMA(afr[ks], bb[cb][ks], acc);
            const int nt = nt0 + i;
            if (lane < 16) {
                if (nt < 16) {               // Q1 half -> bf16 A-frag (elu(x + Qpre))
                    const int col = nt * 16 + lane;
#pragma unroll
                    for (int reg = 0; reg < 4; ++reg)
                        q1bf[reg][col] = __float2bfloat16(eluf(acc[reg] + qpl[reg][col]));
                } else {                     // gh half -> fp32 (+ b_hh)
                    const int col = nt * 16 + lane - 256;
#pragma unroll
                    for (int reg = 0; reg < 4; ++reg)
                        ghl[reg][col] = acc[reg] + bhh[col];
                }
            }
        }
        // preload this step's GRU-input B-frags (independent of z)
        bf16x8 gib[12];
#pragma unroll
        for (int i = 0; i < 6; ++i) {
            const int nt = wv * 6 + i;
            gib[i * 2 + 0] = wpI[(nt * 2 + 0) * 64 + lane];
            gib[i * 2 + 1] = wpI[(nt * 2 + 1) * 64 + lane];
        }
        __syncthreads();

        // ---- posterior stats (waves 0-3, wave = N-tile) ----
        if (wv < 4) {
            bf16x8 a2[8];
#pragma unroll
            for (int ks = 0; ks < 8; ++ks)
                a2[ks] = *(const bf16x8*)&q1bf[am][ks * 32 + aq * 8];
            f32x4 acc = {0.f, 0.f, 0.f, 0.f};
#pragma unroll
            for (int ks = 0; ks < 8; ++ks) acc = MFMA(a2[ks], wpQ[(wv * 8 + ks) * 64 + lane], acc);
            if (lane < 16) {
                const int c = wv * 16 + lane;
                const float bias = bq2l[c];
#pragma unroll
                for (int reg = 0; reg < 4; ++reg) {
                    float v = acc[reg] + bias;
                    float res = (c < 32) ? v : __expf(clip75(v));
                    sq[reg][c] = res;
                    out[((size_t)(blk * 4 + reg) * TT + t) * 416 + 352 + c] = res;
                }
            }
        }
        __syncthreads();

        // ---- z = qm + qs*eps -> xbf ; act -> xbf ----
        if (tid < 128) {
            const int r = tid >> 5, s = tid & 31;
            float z = sq[r][s] + sq[r][32 + s] * noise[((size_t)t * BB + blk * 4 + r) * SS + s];
            out[((size_t)(blk * 4 + r) * TT + t) * 416 + 256 + s] = z;
            xbf[r][s] = __float2bfloat16(z);
        } else if (tid < 160) {
            const int q = tid - 128, r = q >> 3, c = q & 7;
            xbf[r][32 + c] = __float2bfloat16(act[((size_t)(blk * 4 + r) * TT + t) * 8 + c]);
        }
        __syncthreads();

        // ---- gi = [z|act] @ W_ih^T + b_ih ; 6 tiles per wave ----
        {
            bf16x8 ax0 = *(const bf16x8*)&xbf[am][aq * 8];
            bf16x8 ax1 = *(const bf16x8*)&xbf[am][32 + aq * 8];
#pragma unroll
            for (int i = 0; i < 6; ++i) {
                f32x4 acc = {0.f, 0.f, 0.f, 0.f};
                acc = MFMA(ax0, gib[i * 2 + 0], acc);
                acc = MFMA(ax1, gib[i * 2 + 1], acc);
                const int nt = wv * 6 + i;
                if (lane < 16) {
                    const int col = nt * 16 + lane;
#pragma unroll
                    for (int reg = 0; reg < 4; ++reg)
                        gil[reg][col] = acc[reg] + bih[col];
                }
            }
        }
        __syncthreads();

        // ---- GRU elementwise + h/out write ; prefetch next Qpre rows ----
        {
            const int j = tid & 255, rp = tid >> 8;
#pragma unroll
            for (int rr = 0; rr < 2; ++rr) {
                const int r = rp * 2 + rr;
                float rg = sigf(gil[r][j] + ghl[r][j]);
                float ug = sigf(gil[r][256 + j] + ghl[r][256 + j]);
                float ng = tanhf_(gil[r][512 + j] + rg * ghl[r][512 + j]);
                float hold = h32[r][j];
                float hn = (1.f - ug) * ng + ug * hold;
                out[((size_t)(blk * 4 + r) * TT + t) * 416 + j] = hold;
                h32[r][j] = hn;
                hbf[r][j] = __float2bfloat16(hn);
            }
            const int tn = (t + 1 < TT) ? t + 1 : t;
            for (int i = tid; i < 1024; i += 512) {
                const int r = i >> 8, c = i & 255;
                qpl[r][c] = Qpre[((size_t)tn * BB + blk * 4 + r) * 256 + c];
            }
        }
        __syncthreads();
    }
}

extern "C" void kernel_launch(void* const* d_in, const int* in_sizes, int n_in,
                              void* d_out, int out_size, void* d_ws, size_t ws_size,
                              hipStream_t stream)
{
    const float* obs   = (const float*)d_in[0];
    const float* act   = (const float*)d_in[1];
    const float* noise = (const float*)d_in[2];
    const float* W_e1  = (const float*)d_in[3];
    const float* b_e1  = (const float*)d_in[4];
    const float* W_e2  = (const float*)d_in[5];
    const float* b_e2  = (const float*)d_in[6];
    const float* W_ih  = (const float*)d_in[7];
    const float* W_hh  = (const float*)d_in[8];
    const float* b_ih  = (const float*)d_in[9];
    const float* b_hh  = (const float*)d_in[10];
    const float* W_p1  = (const float*)d_in[11];
    const float* b_p1  = (const float*)d_in[12];
    const float* W_p2  = (const float*)d_in[13];
    const float* b_p2  = (const float*)d_in[14];
    const float* W_q1  = (const float*)d_in[15];
    const float* b_q1  = (const float*)d_in[16];
    const float* W_q2  = (const float*)d_in[17];
    const float* b_q2  = (const float*)d_in[18];
    float* outp = (float*)d_out;

    // workspace layout
    const size_t qpre_elems = (size_t)TT * BB * 256;
    float* Qpre = (float*)d_ws;
    __hip_bfloat16* p = (__hip_bfloat16*)(Qpre + qpre_elems);
    __hip_bfloat16* WAf   = p;  p += 1024 * 256;
    __hip_bfloat16* Wq2f  = p;  p += 64 * 256;
    __hip_bfloat16* Wihf  = p;  p += 768 * 64;
    __hip_bfloat16* We1f  = p;  p += 256 * 64;
    __hip_bfloat16* We2f  = p;  p += 256 * 256;
    __hip_bfloat16* Wq1ef = p;  p += 256 * 256;
    __hip_bfloat16* Wp1f  = p;  p += 256 * 256;
    __hip_bfloat16* Wp2f  = p;  p += 64 * 256;
    size_t need = (char*)p - (char*)d_ws;
    if (ws_size < need) return;

    auto pf = [&](const float* s, __hip_bfloat16* d, int N, int Kpad, int Ksrc, int ld, int coff) {
        int tot = N * Kpad;
        prep_frag<<<(tot + 255) / 256, 256, 0, stream>>>(s, d, N, Kpad, Ksrc, ld, coff);
    };
    pf(W_q1, WAf,               256, 256, 256, 512, 0);   // Q1 h-part -> nt 0..15
    pf(W_hh, WAf + 256 * 256,   768, 256, 256, 256, 0);   // gh        -> nt 16..63
    pf(W_q2, Wq2f,               64, 256, 256, 256, 0);
    pf(W_ih, Wihf,              768,  64,  40,  40, 0);
    pf(W_e1, We1f,              256,  64,  64,  64, 0);
    pf(W_e2, We2f,              256, 256, 256, 256, 0);
    pf(W_q1, Wq1ef,             256, 256, 256, 512, 256); // emb-part of W_q1
    pf(W_p1, Wp1f,              256, 256, 256, 256, 0);
    pf(W_p2, Wp2f,               64, 256, 256, 256, 0);

    obs_enc_k<<<dim3((BB * TT) / 32), dim3(256), 0, stream>>>(
        obs, We1f, b_e1, We2f, b_e2, Wq1ef, b_q1, Qpre);

    rssm_seq<<<dim3(BB / 4), dim3(512), 0, stream>>>(
        act, noise, WAf, Wq2f, Wihf, b_hh, b_ih, b_q2, Qpre, outp);

    prior_k<<<dim3((BB * TT) / 32), dim3(256), 0, stream>>>(
        Wp1f, b_p1, Wp2f, b_p2, outp);
}